// Round 9
// baseline (356.658 us; speedup 1.0000x reference)
//
#include <hip/hip_runtime.h>

// Gemma3nAttention: hidden(2,2048,2048) fp32 -> qkv gemm -> per-head rmsnorm ->
// rope -> GQA causal attention (no softmax scale!) -> out-proj -> (2,2048,2048) fp32.
// R15: epilogue rework. R14 evidence: 4-launch fusion saved ~40us of gaps but
// the fused rmsnorm/rope epilogue cost +36us (qkv 80.5->116.8): 32 serial
// 6-step shfl_xor reduction chains + libm cosf/sinf + shfl rope partners.
// New epilogue: (a) partial ssq computed in-register from acc -> LDS partials
// [128][66] -> 128-thread parallel sum -> rn[tok] (no shfl chains);
// (b) rope partner read from the LDS value row (no shfl); (c) __cosf/__sinf
// HW transcendentals. V path unchanged (own-location RMW, no hazard).
// Everything else identical to R14 (prep, flash v8, out gemm, 4 launches).

#define HID  2048
#define NH   8
#define NKV  2
#define HD   256
#define SB   2048
#define BB   2
#define MTOK (BB * SB)                 // 4096
#define NQKV ((NH + 2 * NKV) * HD)     // 3072

typedef _Float16  f16x8 __attribute__((ext_vector_type(8)));
typedef float     f32x4 __attribute__((ext_vector_type(4)));

__device__ __forceinline__ unsigned short f2h(float f) {
  _Float16 h = (_Float16)f;
  return __builtin_bit_cast(unsigned short, h);
}

// async global->LDS, 16B per lane (m97/m104): LDS dest = wave-uniform base +
// lane*16; all call sites satisfy that by construction (thread t -> byte 16t).
__device__ __forceinline__ void async_copy16(const unsigned short* g, unsigned short* l) {
  __builtin_amdgcn_global_load_lds(
      (const __attribute__((address_space(1))) unsigned int*)g,
      (__attribute__((address_space(3))) unsigned int*)l, 16, 0, 0);
}

__device__ __forceinline__ int swz4(int r) { return (r + (r >> 2)) & 3; }

// ---------------------------------------------------------------------------
// GEMM: C[M][N] = A[M][K] * Bt[N][K]^T, fp16 in, fp32 accum. 8 waves, BM=256,
// BN 256/128, BK=32, 4 LDS buffers, 3-tile prefetch, 2 phases/tile, counted
// vmcnt(8/6) with tail drain (R12-verified).
// MODE 2: fp32 store to Cg. MODE 3 (BN=256, qkv): fused per-head rmsnorm+rope
// epilogue -> Qh/Kh (s-major) and Vt (d-major, pi-permuted keys); no Cg.
// ---------------------------------------------------------------------------
template <int MODE, int BN>
__global__ __launch_bounds__(512, 2) void gemm_p2(const unsigned short* __restrict__ A,
                                                  const unsigned short* __restrict__ Bt,
                                                  void* __restrict__ Cg,
                                                  int M, int N, int K,
                                                  const int* __restrict__ pos,
                                                  const float* __restrict__ qw,
                                                  const float* __restrict__ kw,
                                                  unsigned short* __restrict__ Qh,
                                                  unsigned short* __restrict__ Kh,
                                                  unsigned short* __restrict__ Vt) {
  constexpr int WN  = BN / 4;    // per-wave N span
  constexpr int NF  = BN / 64;   // per-wave N frags (4 or 2)
  constexpr int LPTB = BN / 128; // B staging loads per thread per tile (2 or 1)
  __shared__ __align__(16) unsigned short SMG[4 * 256 * 32 + 4 * BN * 32];
  unsigned short* Ash = SMG;
  unsigned short* Bsh = SMG + 4 * 256 * 32;

  const int t = threadIdx.x;
  const int lane = t & 63, w = t >> 6;
  const int quad = lane >> 4, m15 = lane & 15;
  const int wm = w >> 2, wn = w & 3;

  // XCD-bijective block swizzle (nwg % 8 == 0 for both call sites)
  const int nwg = gridDim.x * gridDim.y;
  int bid = blockIdx.y * gridDim.x + blockIdx.x;
  if ((nwg & 7) == 0) bid = (bid & 7) * (nwg >> 3) + (bid >> 3);
  const int bx = bid % gridDim.x, by = bid / gridDim.x;
  const int m0 = by * 256, n0 = bx * BN;

  // ---- staging precompute: thread t stages chunk c = t + j*512 (16B each) ----
  const unsigned short* aSrc[2];
  int aDst[2];
#pragma unroll
  for (int j = 0; j < 2; ++j) {
    const int c = t + j * 512;          // [0,1024): row = c>>2, slot = c&3
    const int row = c >> 2, slot = c & 3;
    aSrc[j] = A + (size_t)(m0 + row) * K + ((slot ^ swz4(row)) * 8);
    aDst[j] = c * 8;
  }
  const unsigned short* bSrc[LPTB];
  int bDst[LPTB];
#pragma unroll
  for (int j = 0; j < LPTB; ++j) {
    const int c = t + j * 512;          // [0, BN*4)
    const int row = c >> 2, slot = c & 3;
    bSrc[j] = Bt + (size_t)(n0 + row) * K + ((slot ^ swz4(row)) * 8);
    bDst[j] = c * 8;
  }

  // ---- fragment read offsets (halfwords, within one buffer) ----
  int offA[8], offB[NF];
#pragma unroll
  for (int i = 0; i < 8; ++i) {
    const int ra = wm * 128 + i * 16 + m15;
    offA[i] = ra * 32 + ((quad ^ swz4(ra)) * 8);
  }
#pragma unroll
  for (int j = 0; j < NF; ++j) {
    const int rb = wn * WN + j * 16 + m15;
    offB[j] = rb * 32 + ((quad ^ swz4(rb)) * 8);
  }

  const f32x4 vz = {0.f, 0.f, 0.f, 0.f};
  f32x4 acc[8][NF];
#pragma unroll
  for (int i = 0; i < 8; ++i)
#pragma unroll
    for (int j = 0; j < NF; ++j) acc[i][j] = vz;

  const int NK = K >> 5;

  // ---- prologue: stage tiles 0,1,2 ----
  for (int pt = 0; pt < 3; ++pt) {
    const int kb = pt * 32;
    unsigned short* ab = &Ash[pt * 8192];
    unsigned short* bb = &Bsh[pt * (BN * 32)];
#pragma unroll
    for (int j = 0; j < 2; ++j) async_copy16(aSrc[j] + kb, ab + aDst[j]);
#pragma unroll
    for (int j = 0; j < LPTB; ++j) async_copy16(bSrc[j] + kb, bb + bDst[j]);
  }
  if constexpr (BN == 256) asm volatile("s_waitcnt vmcnt(8)" ::: "memory");
  else                     asm volatile("s_waitcnt vmcnt(6)" ::: "memory");
  __builtin_amdgcn_s_barrier();

  for (int kt = 0; kt < NK; ++kt) {
    const int buf = kt & 3;
    const unsigned short* Ab = &Ash[buf * 8192];
    const unsigned short* Bb = &Bsh[buf * (BN * 32)];
    const int s3 = kt + 3;
    const int kb3 = s3 * 32;
    unsigned short* a3 = &Ash[(s3 & 3) * 8192];
    unsigned short* b3 = &Bsh[(s3 & 3) * (BN * 32)];
    const bool stage3 = (s3 < NK);

    // ================= phase 0: M-frags 0-3 =================
    f16x8 af[4], bf[NF];
#pragma unroll
    for (int i = 0; i < 4; ++i) af[i] = *(const f16x8*)&Ab[offA[i]];
#pragma unroll
    for (int j = 0; j < NF; ++j) bf[j] = *(const f16x8*)&Bb[offB[j]];
    if (stage3) {
#pragma unroll
      for (int j = 0; j < 2; ++j) async_copy16(aSrc[j] + kb3, a3 + aDst[j]);
    }
    __builtin_amdgcn_s_barrier();
    asm volatile("s_waitcnt lgkmcnt(0)" ::: "memory");
    __builtin_amdgcn_sched_barrier(0);
    __builtin_amdgcn_s_setprio(1);
#pragma unroll
    for (int i = 0; i < 4; ++i)
#pragma unroll
      for (int j = 0; j < NF; ++j)
        acc[i][j] = __builtin_amdgcn_mfma_f32_16x16x32_f16(af[i], bf[j], acc[i][j], 0, 0, 0);
    __builtin_amdgcn_s_setprio(0);
    __builtin_amdgcn_s_barrier();

    // ================= phase 1: M-frags 4-7 =================
    f16x8 ag[4];
#pragma unroll
    for (int i = 0; i < 4; ++i) ag[i] = *(const f16x8*)&Ab[offA[4 + i]];
    if (stage3) {
#pragma unroll
      for (int j = 0; j < LPTB; ++j) async_copy16(bSrc[j] + kb3, b3 + bDst[j]);
    }
    __builtin_amdgcn_s_barrier();
    asm volatile("s_waitcnt lgkmcnt(0)" ::: "memory");
    __builtin_amdgcn_sched_barrier(0);
    __builtin_amdgcn_s_setprio(1);
#pragma unroll
    for (int i = 0; i < 4; ++i)
#pragma unroll
      for (int j = 0; j < NF; ++j)
        acc[4 + i][j] = __builtin_amdgcn_mfma_f32_16x16x32_f16(ag[i], bf[j], acc[4 + i][j], 0, 0, 0);
    __builtin_amdgcn_s_setprio(0);
    // counted vmcnt at tile boundary; tail (last 3 tiles) fully drains.
    if (stage3) {
      if constexpr (BN == 256) asm volatile("s_waitcnt vmcnt(8)" ::: "memory");
      else                     asm volatile("s_waitcnt vmcnt(6)" ::: "memory");
    } else {
      asm volatile("s_waitcnt vmcnt(0)" ::: "memory");
    }
    __builtin_amdgcn_s_barrier();
  }

  if constexpr (MODE == 2) {
    // C/D layout (m89-verified): col = lane&15, row = quad*4 + reg.
#pragma unroll
    for (int i = 0; i < 8; ++i)
#pragma unroll
      for (int j = 0; j < NF; ++j)
#pragma unroll
        for (int r = 0; r < 4; ++r) {
          const int gm = m0 + wm * 128 + i * 16 + quad * 4 + r;
          const int gn = n0 + wn * WN + j * 16 + m15;
          ((float*)Cg)[(size_t)gm * N + gn] = acc[i][j][r];
        }
  } else {
    // ---- MODE 3: fused rmsnorm + rope epilogue (BN == 256) ----
    // slot = bx: 0-7 Q heads, 8-9 K, 10-11 V. Block owns 256 tokens x 256 d,
    // processed in 2 halves of 128 tokens. LDS overlays (SMG = 128KB, dead):
    //   vals fp16 [128][260]  @ byte 0       (66,560)
    //   part f32  [128][66]   @ byte 66,560  (33,792)
    //   rnv  f32  [128]       @ byte 100,352 (512)
    const int st = (bx < 8) ? 0 : (bx < 10 ? 1 : 2);
    constexpr int ES = 260;
    unsigned short* vals = SMG;
    float* part = (float*)((char*)SMG + 66560);
    float* rnv  = (float*)((char*)SMG + 100352);

    const int dn = lane * 4;                 // own dims [dn, dn+4)
    const int dp = (dn + 128) & 255;         // partner dims
    float invf[4], wo_[4] = {1, 1, 1, 1}, wp_[4] = {1, 1, 1, 1};
    if (st < 2) {
      const float* ww = (st == 0) ? qw : kw;
#pragma unroll
      for (int e = 0; e < 4; ++e) {
        invf[e] = __expf(-(float)((dn & 127) + e) * 0.10793368f);  // 1e6^(-j/128)
        wo_[e] = ww[dn + e];
        wp_[e] = ww[dp + e];
      }
    }
    const bool lo = (lane < 32);

    for (int half = 0; half < 2; ++half) {
      // A+B: this half's waves write fp16 values + in-register partial ssq
      if (wm == half) {
#pragma unroll
        for (int i = 0; i < 8; ++i)
#pragma unroll
          for (int r = 0; r < 4; ++r) {
            const int tl = i * 16 + quad * 4 + r;
            float s4 = 0.f;
#pragma unroll
            for (int j = 0; j < NF; ++j) {
              const float v = acc[i][j][r];
              s4 += v * v;
              vals[tl * ES + wn * 64 + j * 16 + m15] = f2h(v);
            }
            part[tl * 66 + wn * 16 + m15] = s4;
          }
      }
      __syncthreads();

      // C: 128 threads reduce 64 partials each -> rn[tok]
      if (t < 128) {
        float s = 0.f;
#pragma unroll
        for (int e = 0; e < 64; ++e) s += part[t * 66 + e];
        rnv[t] = rsqrtf(s * (1.f / 256.f) + 1e-6f);
      }
      __syncthreads();

      // D: all 8 waves, 16 tokens each; no shuffles, HW transcendentals.
#pragma unroll
      for (int ti = 0; ti < 16; ++ti) {
        const int tl = w * 16 + ti;
        const int gtok = m0 + half * 128 + tl;
        const int b = gtok >> 11, s = gtok & 2047;
        const float rn = rnv[tl];
        union { uint2 u; _Float16 h[4]; } rd;
        rd.u = *(const uint2*)&vals[tl * ES + dn];

        if (st < 2) {
          union { uint2 u; _Float16 h[4]; } pr;
          pr.u = *(const uint2*)&vals[tl * ES + dp];
          const float p = (float)pos[gtok];
          union { uint2 u; _Float16 h[4]; } wr;
#pragma unroll
          for (int e = 0; e < 4; ++e) {
            const float y = (float)rd.h[e] * rn * wo_[e];
            const float partner = (float)pr.h[e] * rn * wp_[e];
            const float fr = p * invf[e];
            const float cv = __cosf(fr), sv = __sinf(fr);
            wr.h[e] = (_Float16)(lo ? (y * cv - partner * sv)
                                    : (y * cv + partner * sv));
          }
          unsigned short* dst = (st == 0)
              ? Qh + ((size_t)(b * NH + bx) * SB + s) * HD + dn
              : Kh + ((size_t)(b * NKV + (bx - 8)) * SB + s) * HD + dn;
          *(uint2*)dst = wr.u;
        } else {
          union { uint2 u; _Float16 h[4]; } wr;
#pragma unroll
          for (int e = 0; e < 4; ++e) wr.h[e] = (_Float16)((float)rd.h[e] * rn);
          *(uint2*)&vals[tl * ES + dn] = wr.u;   // own-location RMW: no hazard
        }
      }

      if (st == 2) {
        __syncthreads();  // normalized V fully in LDS
        const int kv = bx - 10;
        // transpose-write: wave handles d = w + 8*rep, lanes cover 128 tokens.
        // pi(s5)=quad*8+g*4+r for s5=g*16+quad*4+r; preserves low 2 bits, so
        // an even token pair (s, s+1) stays adjacent after permutation.
#pragma unroll
        for (int rep = 0; rep < 32; ++rep) {
          const int d = w + 8 * rep;
          const int tp = lane * 2;
          const unsigned short vlo = vals[tp * ES + d];
          const unsigned short vhi = vals[(tp + 1) * ES + d];
          const int gs = m0 + half * 128 + tp;
          const int b = gs >> 11, s = gs & 2047;
          const int s5 = s & 31;
          const int sp = (s & ~31) | (((s5 >> 2) & 3) << 3) | (((s5 >> 4) & 1) << 2) | (s5 & 3);
          *(unsigned int*)&Vt[((size_t)(b * NKV + kv) * HD + d) * SB + sp] =
              (unsigned)vlo | ((unsigned)vhi << 16);
        }
      }
      __syncthreads();  // reads done before next half overwrites LDS
    }
  }
}

// ---------------------------------------------------------------------------
// prep: one launch for hidden fp32->fp16 + both weight transposes.
// blocks [0,8192): cvt; [8192,9728): w_qkv^T; [9728,10752): w_o^T.
// ---------------------------------------------------------------------------
__global__ __launch_bounds__(256) void prep(const float* __restrict__ hidden,
                                            unsigned short* __restrict__ hb,
                                            const float* __restrict__ w_qkv,
                                            unsigned short* __restrict__ wqkvT,
                                            const float* __restrict__ w_o,
                                            unsigned short* __restrict__ woT) {
  __shared__ float tile[64 * 68];
  const int bid = blockIdx.x;
  const int t = threadIdx.x;

  if (bid < 8192) {
    const int i = bid * 256 + t;
    const float4 v = ((const float4*)hidden)[i];
    ushort4 o = {f2h(v.x), f2h(v.y), f2h(v.z), f2h(v.w)};
    ((ushort4*)hb)[i] = o;
    return;
  }

  const float* in;
  unsigned short* out;
  int R, C, r0, c0;
  if (bid < 9728) {
    const int bb = bid - 8192;            // grid 48 x 32
    in = w_qkv; out = wqkvT; R = HID; C = NQKV;
    r0 = (bb / 48) * 64; c0 = (bb % 48) * 64;
  } else {
    const int bb = bid - 9728;            // grid 32 x 32
    in = w_o; out = woT; R = HID; C = HID;
    r0 = (bb / 32) * 64; c0 = (bb % 32) * 64;
  }
#pragma unroll
  for (int p = 0; p < 4; ++p) {
    const int idx = t + p * 256;
    const int rr = idx >> 4, cc = (idx & 15) * 4;
    *(float4*)&tile[rr * 68 + cc] = *(const float4*)&in[(size_t)(r0 + rr) * C + c0 + cc];
  }
  __syncthreads();
#pragma unroll
  for (int p = 0; p < 2; ++p) {
    const int idx = t + p * 256;
    const int dr = idx >> 3, sc = (idx & 7) * 8;
    union { uint4 v; unsigned short s[8]; } o;
#pragma unroll
    for (int e = 0; e < 8; ++e) o.s[e] = f2h(tile[(sc + e) * 68 + dr]);
    *(uint4*)&out[(size_t)(c0 + dr) * R + r0 + sc] = o.v;
  }
}

// ---------------------------------------------------------------------------
// Flash attention v8 (causal, no scale). 8 waves (512 thr) = 2 waves/SIMD,
// grid 256 = 1 block/CU, q-tile PAIR (qa, 31-qa) sequential (uniform 33 tiles).
// Teams split keys (32 each) with independent online softmax, merged per
// q-tile via dead K/V LDS. Swapped operands: S=mfma(K,Q)->S[key][q],
// O=mfma(V,P)->O[d][q]. Lane owns ONE q: softmax reduce = local max + 2 shfl.
// PV key order PERMUTED (pi applied to Vt columns in the gemm epilogue) ->
// PV B-frag is lane-local packing, zero shuffles. T13-lite rescale skip.
// ---------------------------------------------------------------------------
__global__ __launch_bounds__(512, 2) void flash_attn(const unsigned short* __restrict__ Qh,
                                                     const unsigned short* __restrict__ Kh,
                                                     const unsigned short* __restrict__ Vt,  // [B][NKV][D][S] (pi-permuted keys)
                                                     unsigned short* __restrict__ attn) {    // fp16 [B*S][NH*HD]
  // flat LDS: K 64KB | V 64KB | MLx 1KB  (merge O overlays K+V region)
  __shared__ __align__(16) unsigned char SMEM[132096];
  unsigned short* Ksh = (unsigned short*)SMEM;             // [2][64*256]
  unsigned short* Vsh = (unsigned short*)(SMEM + 65536);   // [2][256*64]
  float*         MLx  = (float*)(SMEM + 131072);           // [8][16*2]
  float*         mergeO = (float*)SMEM;                    // overlay [8][128*17]

  const int pairi = blockIdx.x;  // 0..15
  const int h = blockIdx.y, b = blockIdx.z;
  const int kv = h >> 2;
  const int t = threadIdx.x, w = t >> 6, lane = t & 63;
  const int wq = w & 3, team = w >> 2;
  const int quad = lane >> 4, m15 = lane & 15;

  const unsigned short* Kb = Kh + (size_t)(b * NKV + kv) * SB * HD;
  const unsigned short* Vb = Vt + (size_t)(b * NKV + kv) * HD * SB;

  // staging geometry (512 threads, 16B each -> 8KB/shot, 4 shots per 32KB tile)
  const int krow = t >> 5, kchunk = t & 31;   // K: 16 rows x 512B per shot
  const int vrow = t >> 3, vchunk = t & 7;    // V: 64 rows x 128B per shot

  const f32x4 vz = {0.f, 0.f, 0.f, 0.f};

  for (int jb = 0; jb < 2; ++jb) {
    const int qt = jb ? (31 - pairi) : pairi;
    const int q0 = qt * 64, qw0 = q0 + wq * 16;
    const int qlane = qw0 + m15;   // this lane's q row (swapped layout)

    // Q fragments (B-operand): B[k=quad*8+j][col=q=m15]
    f16x8 aq[8];
    const unsigned short* qb = Qh + ((size_t)(b * NH + h) * SB + qw0 + m15) * HD + quad * 8;
#pragma unroll
    for (int ks = 0; ks < 8; ++ks) aq[ks] = *(const f16x8*)(qb + ks * 32);

    f32x4 o[16];  // O[d][q]: d = dbi*16 + quad*4 + r, q = qlane
#pragma unroll
    for (int i = 0; i < 16; ++i) o[i] = vz;
    float mrow = -1e30f, lrow = 0.f;

    const int nkt = (q0 + 64) >> 6;

    // prologue: stage tile 0 into buffer 0
#pragma unroll
    for (int shot = 0; shot < 4; ++shot) {
      const int r = krow + 16 * shot;
      async_copy16(Kb + (size_t)r * HD + ((kchunk ^ (r & 7)) * 8),
                   &Ksh[4096 * shot + t * 8]);
    }
#pragma unroll
    for (int shot = 0; shot < 4; ++shot) {
      const int d = vrow + 64 * shot;
      async_copy16(Vb + (size_t)d * SB + ((vchunk ^ (d & 7)) * 8),
                   &Vsh[4096 * shot + t * 8]);
    }
    __syncthreads();  // drain: tile 0 ready

    for (int kt = 0; kt < nkt; ++kt) {
      const int k0 = kt * 64;
      const int par = kt & 1;

      // stage tile kt+1 into the other buffer (drained by loop-end barrier)
      if (kt + 1 < nkt) {
        const int kn = k0 + 64;
        const int pn = par ^ 1;
#pragma unroll
        for (int shot = 0; shot < 4; ++shot) {
          const int r = krow + 16 * shot;
          async_copy16(Kb + (size_t)(kn + r) * HD + ((kchunk ^ (r & 7)) * 8),
                       &Ksh[pn * 16384 + 4096 * shot + t * 8]);
        }
#pragma unroll
        for (int shot = 0; shot < 4; ++shot) {
          const int d = vrow + 64 * shot;
          async_copy16(Vb + (size_t)d * SB + kn + ((vchunk ^ (d & 7)) * 8),
                       &Vsh[pn * 16384 + 4096 * shot + t * 8]);
        }
      }

      const unsigned short* KB = &Ksh[par * 16384];
      const unsigned short* VB = &Vsh[par * 16384];

      // ---- scores S[32 team keys][16 q] via mfma(A=K, B=Q) ----
      f32x4 sv[2];
      sv[0] = vz; sv[1] = vz;
#pragma unroll
      for (int g = 0; g < 2; ++g) {
        const int key = team * 32 + g * 16 + m15;
        const unsigned short* kr = &KB[key * 256];
        const int sw = (key & 7);
#pragma unroll
        for (int ks = 0; ks < 8; ++ks) {
          const f16x8 ak = *(const f16x8*)&kr[((4 * ks + quad) ^ sw) * 8];
          sv[g] = __builtin_amdgcn_mfma_f32_16x16x32_f16(ak, aq[ks], sv[g], 0, 0, 0);
        }
      }

      // ---- lane-local online softmax (lane owns q=qlane; 8 p-values) ----
      const bool last = (kt == nkt - 1);
      float p2[2][4];
#pragma unroll
      for (int g = 0; g < 2; ++g)
#pragma unroll
        for (int r = 0; r < 4; ++r) {
          float s = sv[g][r];
          if (last && (k0 + team * 32 + g * 16 + quad * 4 + r) > qlane) s = -3.0e38f;
          p2[g][r] = s;
        }
      float tm = fmaxf(fmaxf(fmaxf(p2[0][0], p2[0][1]), fmaxf(p2[0][2], p2[0][3])),
                       fmaxf(fmaxf(p2[1][0], p2[1][1]), fmaxf(p2[1][2], p2[1][3])));
      tm = fmaxf(tm, __shfl_xor(tm, 16));
      tm = fmaxf(tm, __shfl_xor(tm, 32));
      if (!__all(tm <= mrow)) {   // T13-lite: skip rescale when max unchanged
        const float mnew = fmaxf(mrow, tm);
        const float alpha = __expf(mrow - mnew);
        lrow *= alpha;
#pragma unroll
        for (int dbi = 0; dbi < 16; ++dbi) o[dbi] *= alpha;
        mrow = mnew;
      }
      float rs = 0.f;
#pragma unroll
      for (int g = 0; g < 2; ++g)
#pragma unroll
        for (int r = 0; r < 4; ++r) { p2[g][r] = __expf(p2[g][r] - mrow); rs += p2[g][r]; }
      rs += __shfl_xor(rs, 16);
      rs += __shfl_xor(rs, 32);
      lrow += rs;

      // ---- PV B-frag: lane-local (keys pi-permuted in V) ----
      f16x8 bp;
#pragma unroll
      for (int g = 0; g < 2; ++g)
#pragma unroll
        for (int r = 0; r < 4; ++r) bp[g * 4 + r] = (_Float16)p2[g][r];

      // ---- PV via mfma(A=V, B=P): O[d][q] ----
#pragma unroll
      for (int dbi = 0; dbi < 16; ++dbi) {
        const int d = dbi * 16 + m15;
        const f16x8 av = *(const f16x8*)&VB[d * 64 + (((team * 4 + quad) ^ (d & 7)) * 8)];
        o[dbi] = __builtin_amdgcn_mfma_f32_16x16x32_f16(av, bp, o[dbi], 0, 0, 0);
      }

      __syncthreads();  // drains stage(kt+1) vmcnt + guards buffer reuse
    }

    // ---- split-K merge through LDS (K/V buffers dead now) ----
    if (quad == 0) {
      MLx[w * 32 + m15 * 2]     = mrow;
      MLx[w * 32 + m15 * 2 + 1] = lrow;
    }
    {
      float* mo = mergeO + w * 2176;  // [128 d_local][17]
#pragma unroll
      for (int ii = 0; ii < 8; ++ii) {
        const int dbi = team ? ii : (8 + ii);   // write the NON-merged half
#pragma unroll
        for (int r = 0; r < 4; ++r)
          mo[(ii * 16 + quad * 4 + r) * 17 + m15] = o[dbi][r];
      }
    }
    __syncthreads();
    {
      const int pw = w ^ 4;
      const float* pmo = mergeO + pw * 2176;
      const float pm = MLx[pw * 32 + m15 * 2];
      const float pl = MLx[pw * 32 + m15 * 2 + 1];
      const float mm = fmaxf(mrow, pm);
      const float a0 = __expf(mrow - mm);
      const float a1 = __expf(pm - mm);
      const float invl = 1.0f / (a0 * lrow + a1 * pl);
      const int q = qlane;
#pragma unroll
      for (int ii = 0; ii < 8; ++ii) {
        const int dbi = team ? (8 + ii) : ii;   // merge the OTHER half
        union { uint2 u; _Float16 hh[4]; } st;
#pragma unroll
        for (int r = 0; r < 4; ++r) {
          const float po = pmo[(ii * 16 + quad * 4 + r) * 17 + m15];
          st.hh[r] = (_Float16)((a0 * o[dbi][r] + a1 * po) * invl);
        }
        const int dcol = team * 128 + ii * 16 + quad * 4;
        *(uint2*)&attn[(size_t)(b * SB + q) * (NH * HD) + h * HD + dcol] = st.u;
      }
    }
    __syncthreads();  // merge reads done before next jb's staging overwrites
  }
}

// ---------------------------------------------------------------------------
// workspace layout (bytes), 60 MiB, lifetime-based reuse.
// prep: writes hb, wqkvT, woT. qkv gemm: reads hb+wqkvT, writes Qh/Kh/Vt.
// flash: reads Qh/Kh/Vt, writes attnb (over dead hb). out gemm: attnb+woT.
// ---------------------------------------------------------------------------
static constexpr size_t OFF_QH   = 0;                      // 16,777,216
static constexpr size_t OFF_KH   = 16777216;               //  4,194,304
static constexpr size_t OFF_VT   = 20971520;               //  4,194,304
static constexpr size_t OFF_W1T  = 25165824;               // 12,582,912
static constexpr size_t OFF_WOT  = 37748736;               //  8,388,608
static constexpr size_t OFF_HB   = 46137344;               // 16,777,216
static constexpr size_t OFF_ATTN = OFF_HB;                 // 16,777,216 (reuse)

extern "C" void kernel_launch(void* const* d_in, const int* in_sizes, int n_in,
                              void* d_out, int out_size, void* d_ws, size_t ws_size,
                              hipStream_t stream) {
  const float* hidden    = (const float*)d_in[0];
  const int*   positions = (const int*)d_in[1];
  const float* w_qkv     = (const float*)d_in[2];
  const float* w_o       = (const float*)d_in[3];
  const float* qw        = (const float*)d_in[4];
  const float* kw        = (const float*)d_in[5];
  float* out = (float*)d_out;
  char* ws = (char*)d_ws;

  unsigned short* hb    = (unsigned short*)(ws + OFF_HB);
  unsigned short* wqkvT = (unsigned short*)(ws + OFF_W1T);
  unsigned short* woT   = (unsigned short*)(ws + OFF_WOT);
  unsigned short* attnb = (unsigned short*)(ws + OFF_ATTN);
  unsigned short* Qhb   = (unsigned short*)(ws + OFF_QH);
  unsigned short* Khb   = (unsigned short*)(ws + OFF_KH);
  unsigned short* Vtb   = (unsigned short*)(ws + OFF_VT);

  prep<<<dim3(10752), 256, 0, stream>>>(hidden, hb, w_qkv, wqkvT, w_o, woT);

  gemm_p2<3, 256><<<dim3(NQKV / 256, MTOK / 256), 512, 0, stream>>>(
      hb, wqkvT, nullptr, MTOK, NQKV, HID, positions, qw, kw, Qhb, Khb, Vtb);

  flash_attn<<<dim3(16, NH, BB), 512, 0, stream>>>(Qhb, Khb, Vtb, attnb);

  gemm_p2<2, 128><<<dim3(HID / 128, MTOK / 256), 512, 0, stream>>>(
      attnb, woT, out, MTOK, HID, HID, nullptr, nullptr, nullptr, nullptr, nullptr, nullptr);
}

// Round 11
// 318.184 us; speedup vs baseline: 1.1209x; 1.1209x over previous
//
#include <hip/hip_runtime.h>

// Gemma3nAttention: hidden(2,2048,2048) fp32 -> qkv gemm -> per-head rmsnorm ->
// rope -> GQA causal attention (no softmax scale!) -> out-proj -> (2,2048,2048) fp32.
// R17 = R16 resubmit (container infra failure) with one safety tweak: invf is
// recomputed INLINE per element exactly as R14 did (no hoisted invf[4] array,
// so the epilogue's register profile is byte-identical to the proven
// spill-free R14). Only change vs R14: libm cosf/sinf/expf -> HW
// __cosf/__sinf/__expf (numerics verified harmless in R15, absmax 0.03125).
// R15 post-mortem recap: parts-array epilogue spilled acc (+49MB HBM traffic,
// qkv WRITE 24.6->57.6MB, 131.5us); R14's shfl-chain epilogue is spill-free.
// Everything else (prep, flash v8, out gemm, 4 launches) unchanged from R14.

#define HID  2048
#define NH   8
#define NKV  2
#define HD   256
#define SB   2048
#define BB   2
#define MTOK (BB * SB)                 // 4096
#define NQKV ((NH + 2 * NKV) * HD)     // 3072

typedef _Float16  f16x8 __attribute__((ext_vector_type(8)));
typedef float     f32x4 __attribute__((ext_vector_type(4)));

__device__ __forceinline__ unsigned short f2h(float f) {
  _Float16 h = (_Float16)f;
  return __builtin_bit_cast(unsigned short, h);
}

// async global->LDS, 16B per lane (m97/m104): LDS dest = wave-uniform base +
// lane*16; all call sites satisfy that by construction (thread t -> byte 16t).
__device__ __forceinline__ void async_copy16(const unsigned short* g, unsigned short* l) {
  __builtin_amdgcn_global_load_lds(
      (const __attribute__((address_space(1))) unsigned int*)g,
      (__attribute__((address_space(3))) unsigned int*)l, 16, 0, 0);
}

__device__ __forceinline__ int swz4(int r) { return (r + (r >> 2)) & 3; }

// ---------------------------------------------------------------------------
// GEMM: C[M][N] = A[M][K] * Bt[N][K]^T, fp16 in, fp32 accum. 8 waves, BM=256,
// BN 256/128, BK=32, 4 LDS buffers, 3-tile prefetch, 2 phases/tile, counted
// vmcnt(8/6) with tail drain (R12-verified).
// MODE 2: fp32 store to Cg. MODE 3 (BN=256, qkv): fused per-head rmsnorm+rope
// epilogue -> Qh/Kh (s-major) and Vt (d-major, pi-permuted keys); no Cg.
// ---------------------------------------------------------------------------
template <int MODE, int BN>
__global__ __launch_bounds__(512, 2) void gemm_p2(const unsigned short* __restrict__ A,
                                                  const unsigned short* __restrict__ Bt,
                                                  void* __restrict__ Cg,
                                                  int M, int N, int K,
                                                  const int* __restrict__ pos,
                                                  const float* __restrict__ qw,
                                                  const float* __restrict__ kw,
                                                  unsigned short* __restrict__ Qh,
                                                  unsigned short* __restrict__ Kh,
                                                  unsigned short* __restrict__ Vt) {
  constexpr int WN  = BN / 4;    // per-wave N span
  constexpr int NF  = BN / 64;   // per-wave N frags (4 or 2)
  constexpr int LPTB = BN / 128; // B staging loads per thread per tile (2 or 1)
  __shared__ __align__(16) unsigned short SMG[4 * 256 * 32 + 4 * BN * 32];
  unsigned short* Ash = SMG;
  unsigned short* Bsh = SMG + 4 * 256 * 32;

  const int t = threadIdx.x;
  const int lane = t & 63, w = t >> 6;
  const int quad = lane >> 4, m15 = lane & 15;
  const int wm = w >> 2, wn = w & 3;

  // XCD-bijective block swizzle (nwg % 8 == 0 for both call sites)
  const int nwg = gridDim.x * gridDim.y;
  int bid = blockIdx.y * gridDim.x + blockIdx.x;
  if ((nwg & 7) == 0) bid = (bid & 7) * (nwg >> 3) + (bid >> 3);
  const int bx = bid % gridDim.x, by = bid / gridDim.x;
  const int m0 = by * 256, n0 = bx * BN;

  // ---- staging precompute: thread t stages chunk c = t + j*512 (16B each) ----
  const unsigned short* aSrc[2];
  int aDst[2];
#pragma unroll
  for (int j = 0; j < 2; ++j) {
    const int c = t + j * 512;          // [0,1024): row = c>>2, slot = c&3
    const int row = c >> 2, slot = c & 3;
    aSrc[j] = A + (size_t)(m0 + row) * K + ((slot ^ swz4(row)) * 8);
    aDst[j] = c * 8;
  }
  const unsigned short* bSrc[LPTB];
  int bDst[LPTB];
#pragma unroll
  for (int j = 0; j < LPTB; ++j) {
    const int c = t + j * 512;          // [0, BN*4)
    const int row = c >> 2, slot = c & 3;
    bSrc[j] = Bt + (size_t)(n0 + row) * K + ((slot ^ swz4(row)) * 8);
    bDst[j] = c * 8;
  }

  // ---- fragment read offsets (halfwords, within one buffer) ----
  int offA[8], offB[NF];
#pragma unroll
  for (int i = 0; i < 8; ++i) {
    const int ra = wm * 128 + i * 16 + m15;
    offA[i] = ra * 32 + ((quad ^ swz4(ra)) * 8);
  }
#pragma unroll
  for (int j = 0; j < NF; ++j) {
    const int rb = wn * WN + j * 16 + m15;
    offB[j] = rb * 32 + ((quad ^ swz4(rb)) * 8);
  }

  const f32x4 vz = {0.f, 0.f, 0.f, 0.f};
  f32x4 acc[8][NF];
#pragma unroll
  for (int i = 0; i < 8; ++i)
#pragma unroll
    for (int j = 0; j < NF; ++j) acc[i][j] = vz;

  const int NK = K >> 5;

  // ---- prologue: stage tiles 0,1,2 ----
  for (int pt = 0; pt < 3; ++pt) {
    const int kb = pt * 32;
    unsigned short* ab = &Ash[pt * 8192];
    unsigned short* bb = &Bsh[pt * (BN * 32)];
#pragma unroll
    for (int j = 0; j < 2; ++j) async_copy16(aSrc[j] + kb, ab + aDst[j]);
#pragma unroll
    for (int j = 0; j < LPTB; ++j) async_copy16(bSrc[j] + kb, bb + bDst[j]);
  }
  if constexpr (BN == 256) asm volatile("s_waitcnt vmcnt(8)" ::: "memory");
  else                     asm volatile("s_waitcnt vmcnt(6)" ::: "memory");
  __builtin_amdgcn_s_barrier();

  for (int kt = 0; kt < NK; ++kt) {
    const int buf = kt & 3;
    const unsigned short* Ab = &Ash[buf * 8192];
    const unsigned short* Bb = &Bsh[buf * (BN * 32)];
    const int s3 = kt + 3;
    const int kb3 = s3 * 32;
    unsigned short* a3 = &Ash[(s3 & 3) * 8192];
    unsigned short* b3 = &Bsh[(s3 & 3) * (BN * 32)];
    const bool stage3 = (s3 < NK);

    // ================= phase 0: M-frags 0-3 =================
    f16x8 af[4], bf[NF];
#pragma unroll
    for (int i = 0; i < 4; ++i) af[i] = *(const f16x8*)&Ab[offA[i]];
#pragma unroll
    for (int j = 0; j < NF; ++j) bf[j] = *(const f16x8*)&Bb[offB[j]];
    if (stage3) {
#pragma unroll
      for (int j = 0; j < 2; ++j) async_copy16(aSrc[j] + kb3, a3 + aDst[j]);
    }
    __builtin_amdgcn_s_barrier();
    asm volatile("s_waitcnt lgkmcnt(0)" ::: "memory");
    __builtin_amdgcn_sched_barrier(0);
    __builtin_amdgcn_s_setprio(1);
#pragma unroll
    for (int i = 0; i < 4; ++i)
#pragma unroll
      for (int j = 0; j < NF; ++j)
        acc[i][j] = __builtin_amdgcn_mfma_f32_16x16x32_f16(af[i], bf[j], acc[i][j], 0, 0, 0);
    __builtin_amdgcn_s_setprio(0);
    __builtin_amdgcn_s_barrier();

    // ================= phase 1: M-frags 4-7 =================
    f16x8 ag[4];
#pragma unroll
    for (int i = 0; i < 4; ++i) ag[i] = *(const f16x8*)&Ab[offA[4 + i]];
    if (stage3) {
#pragma unroll
      for (int j = 0; j < LPTB; ++j) async_copy16(bSrc[j] + kb3, b3 + bDst[j]);
    }
    __builtin_amdgcn_s_barrier();
    asm volatile("s_waitcnt lgkmcnt(0)" ::: "memory");
    __builtin_amdgcn_sched_barrier(0);
    __builtin_amdgcn_s_setprio(1);
#pragma unroll
    for (int i = 0; i < 4; ++i)
#pragma unroll
      for (int j = 0; j < NF; ++j)
        acc[4 + i][j] = __builtin_amdgcn_mfma_f32_16x16x32_f16(ag[i], bf[j], acc[4 + i][j], 0, 0, 0);
    __builtin_amdgcn_s_setprio(0);
    // counted vmcnt at tile boundary; tail (last 3 tiles) fully drains.
    if (stage3) {
      if constexpr (BN == 256) asm volatile("s_waitcnt vmcnt(8)" ::: "memory");
      else                     asm volatile("s_waitcnt vmcnt(6)" ::: "memory");
    } else {
      asm volatile("s_waitcnt vmcnt(0)" ::: "memory");
    }
    __builtin_amdgcn_s_barrier();
  }

  if constexpr (MODE == 2) {
    // C/D layout (m89-verified): col = lane&15, row = quad*4 + reg.
#pragma unroll
    for (int i = 0; i < 8; ++i)
#pragma unroll
      for (int j = 0; j < NF; ++j)
#pragma unroll
        for (int r = 0; r < 4; ++r) {
          const int gm = m0 + wm * 128 + i * 16 + quad * 4 + r;
          const int gn = n0 + wn * WN + j * 16 + m15;
          ((float*)Cg)[(size_t)gm * N + gn] = acc[i][j][r];
        }
  } else {
    // ---- MODE 3: fused rmsnorm + rope epilogue (BN == 256) ----
    // R14's spill-free structure (shfl-chain ssq, shfl rope partner, inline
    // invf), with HW __cosf/__sinf/__expf (R15-verified numerics).
    // slot = bx: 0-7 Q, 8-9 K, 10-11 V. 256 tokens x 256 d, 2 halves.
    const int st = (bx < 8) ? 0 : (bx < 10 ? 1 : 2);
    constexpr int ES = 260;   // LDS row stride (halfwords): 2-way max conflict
    const int dbase = lane * 4;
    const bool lo = (lane < 32);

    for (int half = 0; half < 2; ++half) {
      // waves of this half dump acc as fp16 into LDS[tok][d]
      if (wm == half) {
#pragma unroll
        for (int i = 0; i < 8; ++i)
#pragma unroll
          for (int j = 0; j < NF; ++j)
#pragma unroll
            for (int r = 0; r < 4; ++r)
              SMG[(i * 16 + quad * 4 + r) * ES + wn * 64 + j * 16 + m15] = f2h(acc[i][j][r]);
      }
      __syncthreads();

      // all 8 waves: 16 tokens each; lane owns dims [dbase, dbase+4)
#pragma unroll
      for (int ti = 0; ti < 16; ++ti) {
        const int tl = w * 16 + ti;
        const int gtok = m0 + half * 128 + tl;
        const int b = gtok >> 11, s = gtok & 2047;
        union { uint2 u; _Float16 h[4]; } rd;
        rd.u = *(const uint2*)&SMG[tl * ES + dbase];
        float y[4];
#pragma unroll
        for (int e = 0; e < 4; ++e) y[e] = (float)rd.h[e];
        float ssq = y[0] * y[0] + y[1] * y[1] + y[2] * y[2] + y[3] * y[3];
#pragma unroll
        for (int off = 1; off < 64; off <<= 1) ssq += __shfl_xor(ssq, off);
        const float rn = rsqrtf(ssq * (1.f / 256.f) + 1e-6f);

        if (st == 0) {
#pragma unroll
          for (int e = 0; e < 4; ++e) y[e] *= rn * qw[dbase + e];
        } else if (st == 1) {
#pragma unroll
          for (int e = 0; e < 4; ++e) y[e] *= rn * kw[dbase + e];
        } else {
#pragma unroll
          for (int e = 0; e < 4; ++e) y[e] *= rn;
        }

        union { uint2 u; _Float16 h[4]; } wr;
        if (st < 2) {
          const float p = (float)pos[gtok];
          const int i0 = dbase & 127;
#pragma unroll
          for (int e = 0; e < 4; ++e) {
            const float partner = __shfl_xor(y[e], 32);
            const float invf = __expf(-(float)(i0 + e) * 0.10793368f);  // 1e6^(-j/128)
            const float fr = p * invf;
            const float cv = __cosf(fr), sv = __sinf(fr);
            wr.h[e] = (_Float16)(lo ? (y[e] * cv - partner * sv)
                                    : (y[e] * cv + partner * sv));
          }
          unsigned short* dst = (st == 0)
              ? Qh + ((size_t)(b * NH + bx) * SB + s) * HD + dbase
              : Kh + ((size_t)(b * NKV + (bx - 8)) * SB + s) * HD + dbase;
          *(uint2*)dst = wr.u;
        } else {
#pragma unroll
          for (int e = 0; e < 4; ++e) wr.h[e] = (_Float16)y[e];
          *(uint2*)&SMG[tl * ES + dbase] = wr.u;   // normalized back to LDS
        }
      }

      if (st == 2) {
        __syncthreads();  // normalized V fully in LDS
        const int kv = bx - 10;
        // transpose-write: wave handles d = w + 8*rep, lanes cover 128 tokens.
        // pi(s5)=quad*8+g*4+r for s5=g*16+quad*4+r; preserves low 2 bits, so
        // an even token pair (s, s+1) stays adjacent after permutation.
#pragma unroll
        for (int rep = 0; rep < 32; ++rep) {
          const int d = w + 8 * rep;
          const int tp = lane * 2;
          const unsigned short vlo = SMG[tp * ES + d];
          const unsigned short vhi = SMG[(tp + 1) * ES + d];
          const int gs = m0 + half * 128 + tp;
          const int b = gs >> 11, s = gs & 2047;
          const int s5 = s & 31;
          const int sp = (s & ~31) | (((s5 >> 2) & 3) << 3) | (((s5 >> 4) & 1) << 2) | (s5 & 3);
          *(unsigned int*)&Vt[((size_t)(b * NKV + kv) * HD + d) * SB + sp] =
              (unsigned)vlo | ((unsigned)vhi << 16);
        }
      }
      __syncthreads();  // reads done before next half overwrites LDS
    }
  }
}

// ---------------------------------------------------------------------------
// prep: one launch for hidden fp32->fp16 + both weight transposes.
// blocks [0,8192): cvt; [8192,9728): w_qkv^T; [9728,10752): w_o^T.
// ---------------------------------------------------------------------------
__global__ __launch_bounds__(256) void prep(const float* __restrict__ hidden,
                                            unsigned short* __restrict__ hb,
                                            const float* __restrict__ w_qkv,
                                            unsigned short* __restrict__ wqkvT,
                                            const float* __restrict__ w_o,
                                            unsigned short* __restrict__ woT) {
  __shared__ float tile[64 * 68];
  const int bid = blockIdx.x;
  const int t = threadIdx.x;

  if (bid < 8192) {
    const int i = bid * 256 + t;
    const float4 v = ((const float4*)hidden)[i];
    ushort4 o = {f2h(v.x), f2h(v.y), f2h(v.z), f2h(v.w)};
    ((ushort4*)hb)[i] = o;
    return;
  }

  const float* in;
  unsigned short* out;
  int R, C, r0, c0;
  if (bid < 9728) {
    const int bb = bid - 8192;            // grid 48 x 32
    in = w_qkv; out = wqkvT; R = HID; C = NQKV;
    r0 = (bb / 48) * 64; c0 = (bb % 48) * 64;
  } else {
    const int bb = bid - 9728;            // grid 32 x 32
    in = w_o; out = woT; R = HID; C = HID;
    r0 = (bb / 32) * 64; c0 = (bb % 32) * 64;
  }
#pragma unroll
  for (int p = 0; p < 4; ++p) {
    const int idx = t + p * 256;
    const int rr = idx >> 4, cc = (idx & 15) * 4;
    *(float4*)&tile[rr * 68 + cc] = *(const float4*)&in[(size_t)(r0 + rr) * C + c0 + cc];
  }
  __syncthreads();
#pragma unroll
  for (int p = 0; p < 2; ++p) {
    const int idx = t + p * 256;
    const int dr = idx >> 3, sc = (idx & 7) * 8;
    union { uint4 v; unsigned short s[8]; } o;
#pragma unroll
    for (int e = 0; e < 8; ++e) o.s[e] = f2h(tile[(sc + e) * 68 + dr]);
    *(uint4*)&out[(size_t)(c0 + dr) * R + r0 + sc] = o.v;
  }
}

// ---------------------------------------------------------------------------
// Flash attention v8 (causal, no scale). 8 waves (512 thr) = 2 waves/SIMD,
// grid 256 = 1 block/CU, q-tile PAIR (qa, 31-qa) sequential (uniform 33 tiles).
// Teams split keys (32 each) with independent online softmax, merged per
// q-tile via dead K/V LDS. Swapped operands: S=mfma(K,Q)->S[key][q],
// O=mfma(V,P)->O[d][q]. Lane owns ONE q: softmax reduce = local max + 2 shfl.
// PV key order PERMUTED (pi applied to Vt columns in the gemm epilogue) ->
// PV B-frag is lane-local packing, zero shuffles. T13-lite rescale skip.
// ---------------------------------------------------------------------------
__global__ __launch_bounds__(512, 2) void flash_attn(const unsigned short* __restrict__ Qh,
                                                     const unsigned short* __restrict__ Kh,
                                                     const unsigned short* __restrict__ Vt,  // [B][NKV][D][S] (pi-permuted keys)
                                                     unsigned short* __restrict__ attn) {    // fp16 [B*S][NH*HD]
  // flat LDS: K 64KB | V 64KB | MLx 1KB  (merge O overlays K+V region)
  __shared__ __align__(16) unsigned char SMEM[132096];
  unsigned short* Ksh = (unsigned short*)SMEM;             // [2][64*256]
  unsigned short* Vsh = (unsigned short*)(SMEM + 65536);   // [2][256*64]
  float*         MLx  = (float*)(SMEM + 131072);           // [8][16*2]
  float*         mergeO = (float*)SMEM;                    // overlay [8][128*17]

  const int pairi = blockIdx.x;  // 0..15
  const int h = blockIdx.y, b = blockIdx.z;
  const int kv = h >> 2;
  const int t = threadIdx.x, w = t >> 6, lane = t & 63;
  const int wq = w & 3, team = w >> 2;
  const int quad = lane >> 4, m15 = lane & 15;

  const unsigned short* Kb = Kh + (size_t)(b * NKV + kv) * SB * HD;
  const unsigned short* Vb = Vt + (size_t)(b * NKV + kv) * HD * SB;

  // staging geometry (512 threads, 16B each -> 8KB/shot, 4 shots per 32KB tile)
  const int krow = t >> 5, kchunk = t & 31;   // K: 16 rows x 512B per shot
  const int vrow = t >> 3, vchunk = t & 7;    // V: 64 rows x 128B per shot

  const f32x4 vz = {0.f, 0.f, 0.f, 0.f};

  for (int jb = 0; jb < 2; ++jb) {
    const int qt = jb ? (31 - pairi) : pairi;
    const int q0 = qt * 64, qw0 = q0 + wq * 16;
    const int qlane = qw0 + m15;   // this lane's q row (swapped layout)

    // Q fragments (B-operand): B[k=quad*8+j][col=q=m15]
    f16x8 aq[8];
    const unsigned short* qb = Qh + ((size_t)(b * NH + h) * SB + qw0 + m15) * HD + quad * 8;
#pragma unroll
    for (int ks = 0; ks < 8; ++ks) aq[ks] = *(const f16x8*)(qb + ks * 32);

    f32x4 o[16];  // O[d][q]: d = dbi*16 + quad*4 + r, q = qlane
#pragma unroll
    for (int i = 0; i < 16; ++i) o[i] = vz;
    float mrow = -1e30f, lrow = 0.f;

    const int nkt = (q0 + 64) >> 6;

    // prologue: stage tile 0 into buffer 0
#pragma unroll
    for (int shot = 0; shot < 4; ++shot) {
      const int r = krow + 16 * shot;
      async_copy16(Kb + (size_t)r * HD + ((kchunk ^ (r & 7)) * 8),
                   &Ksh[4096 * shot + t * 8]);
    }
#pragma unroll
    for (int shot = 0; shot < 4; ++shot) {
      const int d = vrow + 64 * shot;
      async_copy16(Vb + (size_t)d * SB + ((vchunk ^ (d & 7)) * 8),
                   &Vsh[4096 * shot + t * 8]);
    }
    __syncthreads();  // drain: tile 0 ready

    for (int kt = 0; kt < nkt; ++kt) {
      const int k0 = kt * 64;
      const int par = kt & 1;

      // stage tile kt+1 into the other buffer (drained by loop-end barrier)
      if (kt + 1 < nkt) {
        const int kn = k0 + 64;
        const int pn = par ^ 1;
#pragma unroll
        for (int shot = 0; shot < 4; ++shot) {
          const int r = krow + 16 * shot;
          async_copy16(Kb + (size_t)(kn + r) * HD + ((kchunk ^ (r & 7)) * 8),
                       &Ksh[pn * 16384 + 4096 * shot + t * 8]);
        }
#pragma unroll
        for (int shot = 0; shot < 4; ++shot) {
          const int d = vrow + 64 * shot;
          async_copy16(Vb + (size_t)d * SB + kn + ((vchunk ^ (d & 7)) * 8),
                       &Vsh[pn * 16384 + 4096 * shot + t * 8]);
        }
      }

      const unsigned short* KB = &Ksh[par * 16384];
      const unsigned short* VB = &Vsh[par * 16384];

      // ---- scores S[32 team keys][16 q] via mfma(A=K, B=Q) ----
      f32x4 sv[2];
      sv[0] = vz; sv[1] = vz;
#pragma unroll
      for (int g = 0; g < 2; ++g) {
        const int key = team * 32 + g * 16 + m15;
        const unsigned short* kr = &KB[key * 256];
        const int sw = (key & 7);
#pragma unroll
        for (int ks = 0; ks < 8; ++ks) {
          const f16x8 ak = *(const f16x8*)&kr[((4 * ks + quad) ^ sw) * 8];
          sv[g] = __builtin_amdgcn_mfma_f32_16x16x32_f16(ak, aq[ks], sv[g], 0, 0, 0);
        }
      }

      // ---- lane-local online softmax (lane owns q=qlane; 8 p-values) ----
      const bool last = (kt == nkt - 1);
      float p2[2][4];
#pragma unroll
      for (int g = 0; g < 2; ++g)
#pragma unroll
        for (int r = 0; r < 4; ++r) {
          float s = sv[g][r];
          if (last && (k0 + team * 32 + g * 16 + quad * 4 + r) > qlane) s = -3.0e38f;
          p2[g][r] = s;
        }
      float tm = fmaxf(fmaxf(fmaxf(p2[0][0], p2[0][1]), fmaxf(p2[0][2], p2[0][3])),
                       fmaxf(fmaxf(p2[1][0], p2[1][1]), fmaxf(p2[1][2], p2[1][3])));
      tm = fmaxf(tm, __shfl_xor(tm, 16));
      tm = fmaxf(tm, __shfl_xor(tm, 32));
      if (!__all(tm <= mrow)) {   // T13-lite: skip rescale when max unchanged
        const float mnew = fmaxf(mrow, tm);
        const float alpha = __expf(mrow - mnew);
        lrow *= alpha;
#pragma unroll
        for (int dbi = 0; dbi < 16; ++dbi) o[dbi] *= alpha;
        mrow = mnew;
      }
      float rs = 0.f;
#pragma unroll
      for (int g = 0; g < 2; ++g)
#pragma unroll
        for (int r = 0; r < 4; ++r) { p2[g][r] = __expf(p2[g][r] - mrow); rs += p2[g][r]; }
      rs += __shfl_xor(rs, 16);
      rs += __shfl_xor(rs, 32);
      lrow += rs;

      // ---- PV B-frag: lane-local (keys pi-permuted in V) ----
      f16x8 bp;
#pragma unroll
      for (int g = 0; g < 2; ++g)
#pragma unroll
        for (int r = 0; r < 4; ++r) bp[g * 4 + r] = (_Float16)p2[g][r];

      // ---- PV via mfma(A=V, B=P): O[d][q] ----
#pragma unroll
      for (int dbi = 0; dbi < 16; ++dbi) {
        const int d = dbi * 16 + m15;
        const f16x8 av = *(const f16x8*)&VB[d * 64 + (((team * 4 + quad) ^ (d & 7)) * 8)];
        o[dbi] = __builtin_amdgcn_mfma_f32_16x16x32_f16(av, bp, o[dbi], 0, 0, 0);
      }

      __syncthreads();  // drains stage(kt+1) vmcnt + guards buffer reuse
    }

    // ---- split-K merge through LDS (K/V buffers dead now) ----
    if (quad == 0) {
      MLx[w * 32 + m15 * 2]     = mrow;
      MLx[w * 32 + m15 * 2 + 1] = lrow;
    }
    {
      float* mo = mergeO + w * 2176;  // [128 d_local][17]
#pragma unroll
      for (int ii = 0; ii < 8; ++ii) {
        const int dbi = team ? ii : (8 + ii);   // write the NON-merged half
#pragma unroll
        for (int r = 0; r < 4; ++r)
          mo[(ii * 16 + quad * 4 + r) * 17 + m15] = o[dbi][r];
      }
    }
    __syncthreads();
    {
      const int pw = w ^ 4;
      const float* pmo = mergeO + pw * 2176;
      const float pm = MLx[pw * 32 + m15 * 2];
      const float pl = MLx[pw * 32 + m15 * 2 + 1];
      const float mm = fmaxf(mrow, pm);
      const float a0 = __expf(mrow - mm);
      const float a1 = __expf(pm - mm);
      const float invl = 1.0f / (a0 * lrow + a1 * pl);
      const int q = qlane;
#pragma unroll
      for (int ii = 0; ii < 8; ++ii) {
        const int dbi = team ? (8 + ii) : ii;   // merge the OTHER half
        union { uint2 u; _Float16 hh[4]; } st;
#pragma unroll
        for (int r = 0; r < 4; ++r) {
          const float po = pmo[(ii * 16 + quad * 4 + r) * 17 + m15];
          st.hh[r] = (_Float16)((a0 * o[dbi][r] + a1 * po) * invl);
        }
        const int dcol = team * 128 + ii * 16 + quad * 4;
        *(uint2*)&attn[(size_t)(b * SB + q) * (NH * HD) + h * HD + dcol] = st.u;
      }
    }
    __syncthreads();  // merge reads done before next jb's staging overwrites
  }
}

// ---------------------------------------------------------------------------
// workspace layout (bytes), 60 MiB, lifetime-based reuse.
// prep: writes hb, wqkvT, woT. qkv gemm: reads hb+wqkvT, writes Qh/Kh/Vt.
// flash: reads Qh/Kh/Vt, writes attnb (over dead hb). out gemm: attnb+woT.
// ---------------------------------------------------------------------------
static constexpr size_t OFF_QH   = 0;                      // 16,777,216
static constexpr size_t OFF_KH   = 16777216;               //  4,194,304
static constexpr size_t OFF_VT   = 20971520;               //  4,194,304
static constexpr size_t OFF_W1T  = 25165824;               // 12,582,912
static constexpr size_t OFF_WOT  = 37748736;               //  8,388,608
static constexpr size_t OFF_HB   = 46137344;               // 16,777,216
static constexpr size_t OFF_ATTN = OFF_HB;                 // 16,777,216 (reuse)

extern "C" void kernel_launch(void* const* d_in, const int* in_sizes, int n_in,
                              void* d_out, int out_size, void* d_ws, size_t ws_size,
                              hipStream_t stream) {
  const float* hidden    = (const float*)d_in[0];
  const int*   positions = (const int*)d_in[1];
  const float* w_qkv     = (const float*)d_in[2];
  const float* w_o       = (const float*)d_in[3];
  const float* qw        = (const float*)d_in[4];
  const float* kw        = (const float*)d_in[5];
  float* out = (float*)d_out;
  char* ws = (char*)d_ws;

  unsigned short* hb    = (unsigned short*)(ws + OFF_HB);
  unsigned short* wqkvT = (unsigned short*)(ws + OFF_W1T);
  unsigned short* woT   = (unsigned short*)(ws + OFF_WOT);
  unsigned short* attnb = (unsigned short*)(ws + OFF_ATTN);
  unsigned short* Qhb   = (unsigned short*)(ws + OFF_QH);
  unsigned short* Khb   = (unsigned short*)(ws + OFF_KH);
  unsigned short* Vtb   = (unsigned short*)(ws + OFF_VT);

  prep<<<dim3(10752), 256, 0, stream>>>(hidden, hb, w_qkv, wqkvT, w_o, woT);

  gemm_p2<3, 256><<<dim3(NQKV / 256, MTOK / 256), 512, 0, stream>>>(
      hb, wqkvT, nullptr, MTOK, NQKV, HID, positions, qw, kw, Qhb, Khb, Vtb);

  flash_attn<<<dim3(16, NH, BB), 512, 0, stream>>>(Qhb, Khb, Vtb, attnb);

  gemm_p2<2, 128><<<dim3(HID / 128, MTOK / 256), 512, 0, stream>>>(
      attnb, woT, out, MTOK, HID, HID, nullptr, nullptr, nullptr, nullptr, nullptr, nullptr);
}